// Round 13
// baseline (48.195 us; speedup 1.0000x reference)
//
#include <hip/hip_runtime.h>
#include <cstdint>

#define NTYPES 39
#define NA 64
#define TABN (NTYPES*NTYPES)   // 1521
#define REP 3                  // diagnostic: repeat compute to surface in rocprof top-5

typedef float float4v __attribute__((ext_vector_type(4)));
typedef int   int4v   __attribute__((ext_vector_type(4)));

__global__ __launch_bounds__(256) void vcharge_kernel(
    const int*   __restrict__ atoms,
    const float* __restrict__ A,
    const float* __restrict__ Q,
    const float* __restrict__ e,
    const float* __restrict__ s,
    const float* __restrict__ alpha,
    const float* __restrict__ beta_p,
    float*       __restrict__ out)
{
  __shared__ float    tab[TABN];           // signed |e_b - e_a|^beta by (a,b)
  __shared__ float    bw2[8];              // bond weight by (af | aromboth<<2)
  __shared__ uint32_t PRT[4*68];           // 2-bit cols, transposed [word][row]
  __shared__ unsigned long long MK[NA];    // 64-bit Af-nonzero row masks
  __shared__ float    EI[4*NA];            // per-wave partial e_i

  const int tid  = threadIdx.x;
  const int wid  = tid >> 6;
  const int lane = tid & 63;
  const int m    = blockIdx.x;

  // ---- in-kernel table fill (once per block) ----
  const float beta = beta_p[0];
  for (int k = tid; k < TABN; k += 256){
    int a = k / NTYPES;
    int b = k - a*NTYPES;
    float d = e[b] - e[a];
    float t = exp2f(beta * log2f(fabsf(d)));   // d==0: log2->-inf, exp2->0
    tab[k] = (d > 0.f) ? t : ((d < 0.f) ? -t : 0.f);
  }
  if (tid < 8){
    float a0 = alpha[0], a1 = alpha[1], a2 = alpha[2], a3 = alpha[3];
    int af = tid & 3;
    float bv = (af == 1) ? a0 : ((af == 2) ? a1 : ((af == 3) ? a2 : 0.f));
    if ((tid & 4) && af != 0) bv += a3;   // marom needs Af>0 and both aromatic
    bw2[tid] = bv;
  }

  // per-lane atom constants (molecule-invariant)
  const int ty = atoms[m*NA + lane];
  const float sinv = 1.0f / s[ty];
  const float alpha4 = alpha[4];
  const uint64_t AROM = (1ull<<6)|(1ull<<10)|(1ull<<19)|(1ull<<20)|(1ull<<21)|(1ull<<22)|(1ull<<32);
  const int aromt = (int)((AROM >> ty) & 1ull);
  const unsigned long long aromBits = __ballot(aromt);  // identical per wave
  const int aromsel = aromt << 2;

  const int sh  = 2 * (lane & 15);
  const int ibase = wid * 16;

  for (int rep = 0; rep < REP; ++rep){
    // opaque pointer: prevents cross-rep CSE/hoisting of the A loads
    const float* Ab = A + (size_t)m * (NA*NA);
    asm volatile("" : "+v"(Ab));

    // ---- phase 1: load 16KB matrix, quantize via exact Horner, transpose ----
    {
      const float4v* A4 = (const float4v*)Ab;
      float4v v0 = A4[tid*4 + 0];
      float4v v1 = A4[tid*4 + 1];
      float4v v2 = A4[tid*4 + 2];
      float4v v3 = A4[tid*4 + 3];
      float flo = v1[3];
      flo = fmaf(flo, 4.f, v1[2]); flo = fmaf(flo, 4.f, v1[1]);
      flo = fmaf(flo, 4.f, v1[0]); flo = fmaf(flo, 4.f, v0[3]);
      flo = fmaf(flo, 4.f, v0[2]); flo = fmaf(flo, 4.f, v0[1]);
      flo = fmaf(flo, 4.f, v0[0]);
      float fhi = v3[3];
      fhi = fmaf(fhi, 4.f, v3[2]); fhi = fmaf(fhi, 4.f, v3[1]);
      fhi = fmaf(fhi, 4.f, v3[0]); fhi = fmaf(fhi, 4.f, v2[3]);
      fhi = fmaf(fhi, 4.f, v2[2]); fhi = fmaf(fhi, 4.f, v2[1]);
      fhi = fmaf(fhi, 4.f, v2[0]);
      uint32_t pk = (uint32_t)flo | ((uint32_t)fhi << 16);
      PRT[(tid & 3)*68 + (tid >> 2)] = pk;   // transposed: [word][row]
    }
    __syncthreads();   // PRT (and on rep0, tab/bw2) ready

    // ---- pass A (fused): af + ballot row masks + bond-term FMA + tab stash ----
    const uint32_t rpw = PRT[wid*68 + lane];        // A[lane][16w..16w+16)
    const int4v* cb = (const int4v*)&PRT[(lane >> 4)*68 + wid*16];
    float tv[16];
    float ei = 0.f;
    unsigned long long mymk = 0;
    #pragma unroll
    for (int c = 0; c < 4; ++c){
      int4v cw = cb[c];                             // conflict-free b128
      #pragma unroll
      for (int q = 0; q < 4; ++q){
        const int k = c*4 + q;
        uint32_t w   = (uint32_t)cw[q];             // PRT[lane>>4][16w+k]
        uint32_t aij = (w >> sh) & 3u;              // A[i][lane]
        uint32_t aji = (rpw >> (2*k)) & 3u;         // A[lane][i]
        uint32_t af  = aij | aji;                   // Af[i][lane] (disjoint)
        unsigned long long bal = __ballot(af != 0u);
        mymk = (lane == k) ? bal : mymk;
        int arom_i = (int)((aromBits >> (ibase + k)) & 1ull);   // uniform
        int idx = (int)af + (aromsel & (0 - arom_i));
        float bw = bw2[idx];
        int tyi = __builtin_amdgcn_readlane(ty, ibase + k);     // uniform
        float t  = tab[tyi*NTYPES + ty];
        tv[k] = t;
        ei = fmaf(bw, t, ei);
      }
    }
    if (lane < 16) MK[ibase + lane] = mymk;
    __syncthreads();

    // ---- pass B: one3 term via b64 preload + readlane ----
    const unsigned long long mkj = MK[lane];
    const unsigned long long mkv = MK[ibase + (lane & 15)];
    const int vlo = (int)(uint32_t)mkv;
    const int vhi = (int)(uint32_t)(mkv >> 32);
    #pragma unroll
    for (int k = 0; k < 16; ++k){
      uint32_t milo = (uint32_t)__builtin_amdgcn_readlane(vlo, k);
      uint32_t mihi = (uint32_t)__builtin_amdgcn_readlane(vhi, k);
      unsigned long long mki =
          (((unsigned long long)mihi) << 32) | milo;
      float add = ((mki & mkj) != 0ull) ? alpha4 : 0.f;
      ei = fmaf(add, tv[k], ei);
    }
    EI[wid*NA + lane] = ei;
    __syncthreads();

    // ---- epilogue ----
    if (wid == 0){
      float eif = EI[lane] + EI[NA + lane] + EI[2*NA + lane] + EI[3*NA + lane];
      float esv = eif * sinv;
      float sv  = sinv;
      #pragma unroll
      for (int off = 32; off; off >>= 1){
        esv += __shfl_xor(esv, off);
        sv  += __shfl_xor(sv,  off);
      }
      const float lam = (Q[m] + esv) / sv;
      out[(size_t)m*NA + lane] = sinv * (lam - eif);
    }
  }
}

extern "C" void kernel_launch(void* const* d_in, const int* in_sizes, int n_in,
                              void* d_out, int out_size, void* d_ws, size_t ws_size,
                              hipStream_t stream)
{
  const int*   atoms = (const int*)  d_in[0];
  const float* A     = (const float*)d_in[1];
  const float* Q     = (const float*)d_in[2];
  const float* e     = (const float*)d_in[3];
  const float* s     = (const float*)d_in[4];
  const float* alpha = (const float*)d_in[5];
  const float* beta  = (const float*)d_in[6];
  float* out = (float*)d_out;

  const int B = in_sizes[2];                 // Q: one entry per molecule
  hipLaunchKernelGGL(vcharge_kernel, dim3(B), dim3(256), 0, stream,
                     atoms, A, Q, e, s, alpha, beta, out);
}

// Round 14
// 26.223 us; speedup vs baseline: 1.8379x; 1.8379x over previous
//
#include <hip/hip_runtime.h>
#include <cstdint>

#define NTYPES 39
#define NA 64
#define TABN (NTYPES*NTYPES)   // 1521

typedef float float4v __attribute__((ext_vector_type(4)));
typedef int   int4v   __attribute__((ext_vector_type(4)));

__global__ __launch_bounds__(512) void vcharge_kernel(
    const int*   __restrict__ atoms,
    const float* __restrict__ A,
    const float* __restrict__ Q,
    const float* __restrict__ e,
    const float* __restrict__ s,
    const float* __restrict__ alpha,
    const float* __restrict__ beta_p,
    float*       __restrict__ out,
    int B)
{
  __shared__ float    tab[TABN];       // signed |e_b - e_a|^beta by (a,b)
  __shared__ float    bw2[8];          // bond weight by (af | aromboth<<2)
  __shared__ uint32_t PRT[2][4*68];    // per-molecule 2-bit cols [word][row]
  __shared__ unsigned long long MK[2][NA];  // per-molecule row masks
  __shared__ float    EI[2][4*NA];     // per-molecule per-wave partial e_i

  const int tid  = threadIdx.x;        // 0..511
  const int g    = tid >> 8;           // molecule slot in block (0/1)
  const int t    = tid & 255;          // thread within group
  const int wid  = t >> 6;             // i-range wave within group (0..3)
  const int lane = tid & 63;

  const int mm  = blockIdx.x * 2 + g;
  const bool act = (mm < B);
  const int m   = act ? mm : (B - 1);  // clamp: redundant compute, no OOB

  // ---- issue global loads FIRST (latency hidden under table fill) ----
  const float4v* A4 = (const float4v*)(A + (size_t)m * (NA*NA));
  float4v v0 = A4[t*4 + 0];
  float4v v1 = A4[t*4 + 1];
  float4v v2 = A4[t*4 + 2];
  float4v v3 = A4[t*4 + 3];
  const int ty = atoms[m*NA + lane];

  // ---- table fill (3 exp2/log2 chains per thread at 512 threads) ----
  const float beta = beta_p[0];
  for (int k = tid; k < TABN; k += 512){
    int a = k / NTYPES;
    int b = k - a*NTYPES;
    float d = e[b] - e[a];
    float tt = exp2f(beta * log2f(fabsf(d)));   // d==0: log2->-inf, exp2->0
    tab[k] = (d > 0.f) ? tt : ((d < 0.f) ? -tt : 0.f);
  }
  if (tid < 8){
    float a0 = alpha[0], a1 = alpha[1], a2 = alpha[2], a3 = alpha[3];
    int af = tid & 3;
    float bv = (af == 1) ? a0 : ((af == 2) ? a1 : ((af == 3) ? a2 : 0.f));
    if ((tid & 4) && af != 0) bv += a3;   // marom needs Af>0 and both aromatic
    bw2[tid] = bv;
  }

  // ---- quantize via exact float Horner, store transposed ----
  // thread t: row r = t>>2, cols [16*(t&3), +16)
  {
    float flo = v1[3];
    flo = fmaf(flo, 4.f, v1[2]); flo = fmaf(flo, 4.f, v1[1]);
    flo = fmaf(flo, 4.f, v1[0]); flo = fmaf(flo, 4.f, v0[3]);
    flo = fmaf(flo, 4.f, v0[2]); flo = fmaf(flo, 4.f, v0[1]);
    flo = fmaf(flo, 4.f, v0[0]);
    float fhi = v3[3];
    fhi = fmaf(fhi, 4.f, v3[2]); fhi = fmaf(fhi, 4.f, v3[1]);
    fhi = fmaf(fhi, 4.f, v3[0]); fhi = fmaf(fhi, 4.f, v2[3]);
    fhi = fmaf(fhi, 4.f, v2[2]); fhi = fmaf(fhi, 4.f, v2[1]);
    fhi = fmaf(fhi, 4.f, v2[0]);
    uint32_t pk = (uint32_t)flo | ((uint32_t)fhi << 16);
    PRT[g][(t & 3)*68 + (t >> 2)] = pk;   // transposed: [word][row]
  }

  // per-lane atom constants
  const float sinv = 1.0f / s[ty];
  const float alpha4 = alpha[4];
  const uint64_t AROM = (1ull<<6)|(1ull<<10)|(1ull<<19)|(1ull<<20)|(1ull<<21)|(1ull<<22)|(1ull<<32);
  const int aromt = (int)((AROM >> ty) & 1ull);
  const unsigned long long aromBits = __ballot(aromt);  // per-wave == per-molecule
  const int aromsel = aromt << 2;

  __syncthreads();   // tab/bw2/PRT ready

  // ---- pass A (fused): af + ballot row masks + bond-term FMA + tab stash ----
  const int sh  = 2 * (lane & 15);
  const uint32_t rpw = PRT[g][wid*68 + lane];        // A[lane][16w..16w+16)
  const int4v* cb = (const int4v*)&PRT[g][(lane >> 4)*68 + wid*16];
  const int ibase = wid * 16;
  float tv[16];
  float ei = 0.f;
  unsigned long long mymk = 0;
  #pragma unroll
  for (int c = 0; c < 4; ++c){
    int4v cw = cb[c];                             // conflict-free b128
    #pragma unroll
    for (int q = 0; q < 4; ++q){
      const int k = c*4 + q;
      uint32_t w   = (uint32_t)cw[q];             // PRT[lane>>4][16w+k]
      uint32_t aij = (w >> sh) & 3u;              // A[i][lane]
      uint32_t aji = (rpw >> (2*k)) & 3u;         // A[lane][i]
      uint32_t af  = aij | aji;                   // Af[i][lane] (disjoint)
      unsigned long long bal = __ballot(af != 0u);
      mymk = (lane == k) ? bal : mymk;
      int arom_i = (int)((aromBits >> (ibase + k)) & 1ull);   // uniform
      int idx = (int)af + (aromsel & (0 - arom_i));
      float bw = bw2[idx];
      int tyi = __builtin_amdgcn_readlane(ty, ibase + k);     // uniform
      float tt = tab[tyi*NTYPES + ty];
      tv[k] = tt;
      ei = fmaf(bw, tt, ei);
    }
  }
  if (lane < 16) MK[g][ibase + lane] = mymk;
  __syncthreads();

  // ---- pass B: one3 term via b64 preload + readlane ----
  const unsigned long long mkj = MK[g][lane];
  const unsigned long long mkv = MK[g][ibase + (lane & 15)];
  const int vlo = (int)(uint32_t)mkv;
  const int vhi = (int)(uint32_t)(mkv >> 32);
  #pragma unroll
  for (int k = 0; k < 16; ++k){
    uint32_t milo = (uint32_t)__builtin_amdgcn_readlane(vlo, k);
    uint32_t mihi = (uint32_t)__builtin_amdgcn_readlane(vhi, k);
    unsigned long long mki =
        (((unsigned long long)mihi) << 32) | milo;
    float add = ((mki & mkj) != 0ull) ? alpha4 : 0.f;
    ei = fmaf(add, tv[k], ei);
  }
  EI[g][wid*NA + lane] = ei;
  __syncthreads();

  // ---- epilogue: wave 0 of each group combines, solves, writes ----
  if (act && wid == 0){
    float eif = EI[g][lane] + EI[g][NA + lane]
              + EI[g][2*NA + lane] + EI[g][3*NA + lane];
    float esv = eif * sinv;
    float sv  = sinv;
    #pragma unroll
    for (int off = 32; off; off >>= 1){
      esv += __shfl_xor(esv, off);
      sv  += __shfl_xor(sv,  off);
    }
    const float lam = (Q[m] + esv) / sv;
    out[(size_t)m*NA + lane] = sinv * (lam - eif);
  }
}

extern "C" void kernel_launch(void* const* d_in, const int* in_sizes, int n_in,
                              void* d_out, int out_size, void* d_ws, size_t ws_size,
                              hipStream_t stream)
{
  const int*   atoms = (const int*)  d_in[0];
  const float* A     = (const float*)d_in[1];
  const float* Q     = (const float*)d_in[2];
  const float* e     = (const float*)d_in[3];
  const float* s     = (const float*)d_in[4];
  const float* alpha = (const float*)d_in[5];
  const float* beta  = (const float*)d_in[6];
  float* out = (float*)d_out;

  const int B = in_sizes[2];                 // Q: one entry per molecule
  const int grid = (B + 1) / 2;              // 2 molecules per block
  hipLaunchKernelGGL(vcharge_kernel, dim3(grid), dim3(512), 0, stream,
                     atoms, A, Q, e, s, alpha, beta, out, B);
}

// Round 15
// 25.762 us; speedup vs baseline: 1.8708x; 1.0179x over previous
//
#include <hip/hip_runtime.h>
#include <cstdint>

#define NTYPES 39
#define NA 64
#define TABN (NTYPES*NTYPES)   // 1521

typedef float float4v __attribute__((ext_vector_type(4)));
typedef int   int4v   __attribute__((ext_vector_type(4)));

__global__ __launch_bounds__(256) void vcharge_kernel(
    const int*   __restrict__ atoms,
    const float* __restrict__ A,
    const float* __restrict__ Q,
    const float* __restrict__ e,
    const float* __restrict__ s,
    const float* __restrict__ alpha,
    const float* __restrict__ beta_p,
    float*       __restrict__ out)
{
  __shared__ float    tab[TABN];           // signed |e_b - e_a|^beta by (a,b)
  __shared__ float    bw2[8];              // bond weight by (af | aromboth<<2)
  __shared__ uint32_t PRT[4*68];           // 2-bit cols, transposed [word][row]
  __shared__ unsigned long long MK[NA];    // 64-bit Af-nonzero row masks
  __shared__ float    EI[4*NA];            // per-wave partial e_i

  const int tid  = threadIdx.x;
  const int wid  = tid >> 6;
  const int lane = tid & 63;
  const int m    = blockIdx.x;

  // ---- in-kernel table fill (once per block) ----
  const float beta = beta_p[0];
  for (int k = tid; k < TABN; k += 256){
    int a = k / NTYPES;
    int b = k - a*NTYPES;
    float d = e[b] - e[a];
    float t = exp2f(beta * log2f(fabsf(d)));   // d==0: log2->-inf, exp2->0
    tab[k] = (d > 0.f) ? t : ((d < 0.f) ? -t : 0.f);
  }
  if (tid < 8){
    float a0 = alpha[0], a1 = alpha[1], a2 = alpha[2], a3 = alpha[3];
    int af = tid & 3;
    float bv = (af == 1) ? a0 : ((af == 2) ? a1 : ((af == 3) ? a2 : 0.f));
    if ((tid & 4) && af != 0) bv += a3;   // marom needs Af>0 and both aromatic
    bw2[tid] = bv;
  }

  // ---- phase 1: TRIANGLE-AWARE loads (A is triu(k=1): skip all-zero chunks) ----
  // thread t: row r = t>>2, cols [16*(t&3), +16); chunk l covers cols 16(t&3)+4l..+3
  {
    const float4v* A4 = (const float4v*)(A + (size_t)m * (NA*NA));
    const int r  = tid >> 2;
    const int c0 = 16 * (tid & 3);
    const float4v z = {0.f, 0.f, 0.f, 0.f};
    float4v v0 = (c0 + 3  > r) ? A4[tid*4 + 0] : z;
    float4v v1 = (c0 + 7  > r) ? A4[tid*4 + 1] : z;
    float4v v2 = (c0 + 11 > r) ? A4[tid*4 + 2] : z;
    float4v v3 = (c0 + 15 > r) ? A4[tid*4 + 3] : z;
    float flo = v1[3];
    flo = fmaf(flo, 4.f, v1[2]); flo = fmaf(flo, 4.f, v1[1]);
    flo = fmaf(flo, 4.f, v1[0]); flo = fmaf(flo, 4.f, v0[3]);
    flo = fmaf(flo, 4.f, v0[2]); flo = fmaf(flo, 4.f, v0[1]);
    flo = fmaf(flo, 4.f, v0[0]);
    float fhi = v3[3];
    fhi = fmaf(fhi, 4.f, v3[2]); fhi = fmaf(fhi, 4.f, v3[1]);
    fhi = fmaf(fhi, 4.f, v3[0]); fhi = fmaf(fhi, 4.f, v2[3]);
    fhi = fmaf(fhi, 4.f, v2[2]); fhi = fmaf(fhi, 4.f, v2[1]);
    fhi = fmaf(fhi, 4.f, v2[0]);
    uint32_t pk = (uint32_t)flo | ((uint32_t)fhi << 16);
    PRT[(tid & 3)*68 + (tid >> 2)] = pk;   // transposed: [word][row]
  }

  // per-lane atom constants (overlap with phase 1)
  const int ty = atoms[m*NA + lane];
  const float sinv = 1.0f / s[ty];
  const float alpha4 = alpha[4];
  const uint64_t AROM = (1ull<<6)|(1ull<<10)|(1ull<<19)|(1ull<<20)|(1ull<<21)|(1ull<<22)|(1ull<<32);
  const int aromt = (int)((AROM >> ty) & 1ull);
  const unsigned long long aromBits = __ballot(aromt);  // identical per wave
  const int aromsel = aromt << 2;

  __syncthreads();

  // ---- pass A (fused): af + ballot row masks + bond-term FMA + tab stash ----
  const int sh  = 2 * (lane & 15);
  const uint32_t rpw = PRT[wid*68 + lane];        // A[lane][16w..16w+16)
  const int4v* cb = (const int4v*)&PRT[(lane >> 4)*68 + wid*16];
  const int ibase = wid * 16;
  float tv[16];                                   // stashed tab values (VGPRs)
  float ei = 0.f;
  unsigned long long mymk = 0;                    // own row mask (lane<16 valid)
  #pragma unroll
  for (int c = 0; c < 4; ++c){
    int4v cw = cb[c];                             // 4 col-words, conflict-free b128
    #pragma unroll
    for (int q = 0; q < 4; ++q){
      const int k = c*4 + q;
      uint32_t w   = (uint32_t)cw[q];             // PRT[lane>>4][16w+k]
      uint32_t aij = (w >> sh) & 3u;              // A[i][lane]
      uint32_t aji = (rpw >> (2*k)) & 3u;         // A[lane][i]
      uint32_t af  = aij | aji;                   // Af[i][lane] (disjoint)
      unsigned long long bal = __ballot(af != 0u);// full row-i nonzero mask
      mymk = (lane == k) ? bal : mymk;
      int arom_i = (int)((aromBits >> (ibase + k)) & 1ull);   // uniform scalar
      int idx = (int)af + (aromsel & (0 - arom_i));
      float bw = bw2[idx];
      int tyi = __builtin_amdgcn_readlane(ty, ibase + k);     // uniform
      float t  = tab[tyi*NTYPES + ty];
      tv[k] = t;
      ei = fmaf(bw, t, ei);
    }
  }
  if (lane < 16) MK[ibase + lane] = mymk;
  __syncthreads();

  // ---- pass B: one3 term via b64 preload + readlane (no per-k LDS) ----
  const unsigned long long mkj = MK[lane];               // own row mask
  const unsigned long long mkv = MK[ibase + (lane & 15)];// wave's 16 masks
  const int vlo = (int)(uint32_t)mkv;
  const int vhi = (int)(uint32_t)(mkv >> 32);
  #pragma unroll
  for (int k = 0; k < 16; ++k){
    uint32_t milo = (uint32_t)__builtin_amdgcn_readlane(vlo, k);
    uint32_t mihi = (uint32_t)__builtin_amdgcn_readlane(vhi, k);
    unsigned long long mki =
        (((unsigned long long)mihi) << 32) | milo;       // MK[ibase+k]
    float add = ((mki & mkj) != 0ull) ? alpha4 : 0.f;
    ei = fmaf(add, tv[k], ei);
  }
  EI[wid*NA + lane] = ei;
  __syncthreads();

  // ---- epilogue: wave 0 combines partials, solves, writes ----
  if (wid == 0){
    float eif = EI[lane] + EI[NA + lane] + EI[2*NA + lane] + EI[3*NA + lane];
    float esv = eif * sinv;
    float sv  = sinv;
    #pragma unroll
    for (int off = 32; off; off >>= 1){
      esv += __shfl_xor(esv, off);
      sv  += __shfl_xor(sv,  off);
    }
    const float lam = (Q[m] + esv) / sv;
    out[(size_t)m*NA + lane] = sinv * (lam - eif);
  }
}

extern "C" void kernel_launch(void* const* d_in, const int* in_sizes, int n_in,
                              void* d_out, int out_size, void* d_ws, size_t ws_size,
                              hipStream_t stream)
{
  const int*   atoms = (const int*)  d_in[0];
  const float* A     = (const float*)d_in[1];
  const float* Q     = (const float*)d_in[2];
  const float* e     = (const float*)d_in[3];
  const float* s     = (const float*)d_in[4];
  const float* alpha = (const float*)d_in[5];
  const float* beta  = (const float*)d_in[6];
  float* out = (float*)d_out;

  const int B = in_sizes[2];                 // Q: one entry per molecule
  hipLaunchKernelGGL(vcharge_kernel, dim3(B), dim3(256), 0, stream,
                     atoms, A, Q, e, s, alpha, beta, out);
}